// Round 9
// baseline (116.065 us; speedup 1.0000x reference)
//
#include <hip/hip_runtime.h>
#include <utility>

// CGCoupler METADATA=[128,128,128,128], max_l=3, parity=0, overlap_out=True,
// trunc_in=True. Indices collapse to slot*128+channel (slot in [0,16)).
// Sparsity STRUCTURE is compile-time (superset via |m|-coupling rules: 284
// entries, 70 (i1,i2) pairs); runtime coefficients are scattered per block
// into LDS (dense [i1][i2][io] cube -> compact entry-order ccs[]), with the
// 32 input loads issued FIRST so HBM latency covers the table build.
// Single kernel: no prep dispatch, no d_ws, no inter-kernel gap.

#define NSLOT 16

struct Ent { unsigned char i1, i2, io, pad; };

struct Tab {
    Ent ent[320];               // grouped by (i1,i2) pair
    unsigned char p1[80], p2[80];
    short ps[81];               // pair segment starts into ent[]
    int npair, nent;
};

constexpr int slotof(int l, int m) { return l * l + m + l; }

constexpr bool triple_ok(int lo, int l1, int l2) {
    if (l1 + l2 > 3) return false;          // trunc_in, max_l=3
    if (l1 + l2 < lo) return false;
    int d = l1 - l2; if (d < 0) d = -d;
    return d <= lo;
}

constexpr Tab build_tab() {
    Tab t{};
    Ent raw[512]{}; int n = 0;
    for (int lo = 0; lo <= 3; ++lo)
        for (int l1 = 0; l1 <= 3; ++l1)
            for (int l2 = 0; l2 <= 3; ++l2) {
                if (!triple_ok(lo, l1, l2)) continue;
                for (int m1 = -l1; m1 <= l1; ++m1)
                    for (int m2 = -l2; m2 <= l2; ++m2)
                        for (int mo = -lo; mo <= lo; ++mo) {
                            int a1 = m1 < 0 ? -m1 : m1, a2 = m2 < 0 ? -m2 : m2;
                            int ao = mo < 0 ? -mo : mo;
                            int s = a1 + a2, d = a1 - a2; if (d < 0) d = -d;
                            if (ao != s && ao != d) continue;
                            raw[n].i1 = (unsigned char)slotof(l1, m1);
                            raw[n].i2 = (unsigned char)slotof(l2, m2);
                            raw[n].io = (unsigned char)slotof(lo, mo);
                            ++n;
                        }
            }
    int np = 0, ne = 0;
    for (int a = 0; a < NSLOT; ++a)
        for (int b = 0; b < NSLOT; ++b) {
            int cnt = 0;
            for (int k = 0; k < n; ++k)
                if (raw[k].i1 == a && raw[k].i2 == b) { t.ent[ne++] = raw[k]; ++cnt; }
            if (cnt) {
                t.p1[np] = (unsigned char)a; t.p2[np] = (unsigned char)b;
                t.ps[np] = (short)(ne - cnt); ++np;
            }
        }
    t.ps[np] = (short)ne; t.npair = np; t.nent = ne;
    return t;
}

__device__ constexpr Tab TT = build_tab();
constexpr int NENT  = build_tab().nent;
constexpr int NPAIR = build_tab().npair;
static_assert(NENT <= 320 && NPAIR <= 80, "table overflow");

// ---- static FMA stream emission (all indices template-constant) ----
template<int J>
__device__ __forceinline__ void fma_ent(const float* cc, const float2 p, float2* acc) {
    constexpr int io = TT.ent[J].io;
    const float c = cc[J];                  // LDS, compile-time offset, broadcast
    acc[io].x = fmaf(c, p.x, acc[io].x);
    acc[io].y = fmaf(c, p.y, acc[io].y);
}

template<int P, int... Js>
__device__ __forceinline__ void pair_body(const float2* a, const float2* b,
                                          const float* cc, float2* acc,
                                          std::integer_sequence<int, Js...>) {
    constexpr int i1 = TT.p1[P], i2 = TT.p2[P], s0 = TT.ps[P];
    const float2 p = make_float2(a[i1].x * b[i2].x, a[i1].y * b[i2].y);
    (fma_ent<s0 + Js>(cc, p, acc), ...);
}

template<int... Ps>
__device__ __forceinline__ void all_pairs(const float2* a, const float2* b,
                                          const float* cc, float2* acc,
                                          std::integer_sequence<int, Ps...>) {
    (pair_body<Ps>(a, b, cc, acc,
         std::make_integer_sequence<int, (int)(TT.ps[Ps + 1] - TT.ps[Ps])>{}), ...);
}

// ---- single fused kernel: per-block cc build + register-resident coupling ----
__global__ __launch_bounds__(256) void couple_kernel(
        const float* __restrict__ x1, const float* __restrict__ x2,
        const float* __restrict__ cg, const int* __restrict__ r1,
        const int* __restrict__ r2, const int* __restrict__ ro,
        int K, float* __restrict__ out) {
    __shared__ float dense[NSLOT * NSLOT * NSLOT];   // 16 KB [i1][i2][io]
    __shared__ float ccs[NENT];

    const int tid = threadIdx.x;
    const int row = (blockIdx.x << 2) + (tid >> 6);  // 4 rows per block
    const int ch  = (tid & 63) << 1;                 // even channel 0..126
    const long long base = (long long)row * 2048 + ch;

    // issue all 32 input loads FIRST: HBM latency overlaps the cc build below
    float2 a[NSLOT], b[NSLOT];
    #pragma unroll
    for (int s = 0; s < NSLOT; ++s) {
        a[s] = *(const float2*)(x1 + base + (s << 7));
        b[s] = *(const float2*)(x2 + base + (s << 7));
    }

    // build coefficient table in LDS (K unique data entries -> dense -> compact)
    for (int i = tid; i < NSLOT * NSLOT * NSLOT; i += 256) dense[i] = 0.f;
    __syncthreads();
    for (int k = tid; k < K; k += 256) {
        const int t = k << 7;                        // ns==0 of each 128-run
        dense[((r1[t] >> 7) << 8) | ((r2[t] >> 7) << 4) | (ro[t] >> 7)] = cg[t];
    }
    __syncthreads();
    for (int j = tid; j < NENT; j += 256) {
        const Ent e = TT.ent[j];
        ccs[j] = dense[((int)e.i1 << 8) | ((int)e.i2 << 4) | (int)e.io];
    }
    __syncthreads();

    float2 acc[NSLOT];
    #pragma unroll
    for (int s = 0; s < NSLOT; ++s) acc[s] = make_float2(0.f, 0.f);

    all_pairs(a, b, ccs, acc, std::make_integer_sequence<int, NPAIR>{});

    #pragma unroll
    for (int s = 0; s < NSLOT; ++s)
        *(float2*)(out + base + (s << 7)) = acc[s];
}

extern "C" void kernel_launch(void* const* d_in, const int* in_sizes, int n_in,
                              void* d_out, int out_size, void* d_ws, size_t ws_size,
                              hipStream_t stream) {
    const float* x1 = (const float*)d_in[0];
    const float* x2 = (const float*)d_in[1];
    const float* cg = (const float*)d_in[2];
    const int*   r1 = (const int*)d_in[3];
    const int*   r2 = (const int*)d_in[4];
    const int*   ro = (const int*)d_in[5];
    float* out = (float*)d_out;

    const int T = in_sizes[2];
    const int K = T >> 7;                   // actual unique entries (~150)
    const int B = in_sizes[0] / 2048;       // 4096 rows

    couple_kernel<<<B / 4, 256, 0, stream>>>(x1, x2, cg, r1, r2, ro, K, out);
}